// Round 3
// baseline (178.154 us; speedup 1.0000x reference)
//
#include <hip/hip_runtime.h>
#include <hip/hip_bf16.h>

// Problem geometry (fixed by the reference)
constexpr int B = 16, K = 100, H = 120, W = 160;
constexpr int HW  = H * W;          // 19200
constexpr int NF4 = HW / 4;         // 4800 float4 per map
constexpr int BK  = B * K;          // 1600 maps per tensor
constexpr int W4  = W / 4;          // 40 float4 per row

// Flat f32 output layout (concatenated in reference return order)
constexpr size_t OFF_DK   = 0;                       // Dk        [B,K,H,W]
constexpr size_t OFF_KP   = (size_t)BK * HW;         // keypoint  [B,3K,3]
constexpr size_t OFF_ZETA = OFF_KP + (size_t)B*3*K*3;// get_zeta  [B,K]
constexpr size_t OFF_TFDK = OFF_ZETA + BK;           // tf_Dk     [B,K,H,W]
constexpr size_t OFF_TFKP = OFF_TFDK + (size_t)BK*HW;// tf_keypoint [B,3K,3]

typedef float f32x4 __attribute__((ext_vector_type(4)));   // native clang vector

__device__ __forceinline__ float sigmoidf(float x) {
    return 1.0f / (1.0f + expf(-x));
}

// Kernel 1: sigmoid + per-map reductions.
// grid.x = 2*BK blocks; block handles one (tensor, b, k) map.
// 2x-unrolled paired float4 loads (32B/lane in flight), nontemporal streams.
__global__ __launch_bounds__(256)
void sigmoid_reduce_kernel(const float* __restrict__ Rk,
                           const float* __restrict__ tfRk,
                           float* __restrict__ out,
                           double* __restrict__ ws) {
    const int blk    = blockIdx.x;
    const int tensor = (blk >= BK) ? 1 : 0;
    const int bk     = blk - tensor * BK;
    const float* src = tensor ? tfRk : Rk;
    float*       dst = out + (tensor ? OFF_TFDK : OFF_DK);

    const f32x4* __restrict__ s4 = (const f32x4*)(src + (size_t)bk * HW);
    f32x4*       __restrict__ d4 = (f32x4*)(dst + (size_t)bk * HW);

    const int tid = threadIdx.x;
    double sum = 0.0, sx = 0.0, sy = 0.0;

    // pairs: i0 = 512*n + 2*tid, i1 = i0+1.  NF4=4800 is even, so pairs never split.
    for (int i0 = 2 * tid; i0 < NF4; i0 += 512) {
        const int i1 = i0 + 1;
        f32x4 va = __builtin_nontemporal_load(s4 + i0);
        f32x4 vb = __builtin_nontemporal_load(s4 + i1);

        f32x4 oa, ob;
        oa.x = sigmoidf(va.x); oa.y = sigmoidf(va.y);
        oa.z = sigmoidf(va.z); oa.w = sigmoidf(va.w);
        ob.x = sigmoidf(vb.x); ob.y = sigmoidf(vb.y);
        ob.z = sigmoidf(vb.z); ob.w = sigmoidf(vb.w);

        __builtin_nontemporal_store(oa, d4 + i0);
        __builtin_nontemporal_store(ob, d4 + i1);

        {
            const int y  = i0 / W4;
            const int x0 = (i0 - y * W4) * 4;
            const double d0 = oa.x, d1 = oa.y, d2 = oa.z, d3 = oa.w;
            const double rs = d0 + d1 + d2 + d3;
            sum += rs;
            sy  += rs * (double)y;
            sx  += d0 * (double)(x0)     + d1 * (double)(x0 + 1)
                 + d2 * (double)(x0 + 2) + d3 * (double)(x0 + 3);
        }
        {
            const int y  = i1 / W4;
            const int x0 = (i1 - y * W4) * 4;
            const double d0 = ob.x, d1 = ob.y, d2 = ob.z, d3 = ob.w;
            const double rs = d0 + d1 + d2 + d3;
            sum += rs;
            sy  += rs * (double)y;
            sx  += d0 * (double)(x0)     + d1 * (double)(x0 + 1)
                 + d2 * (double)(x0 + 2) + d3 * (double)(x0 + 3);
        }
    }

    // wave (64-lane) reduction
    for (int off = 32; off > 0; off >>= 1) {
        sum += __shfl_down(sum, off);
        sx  += __shfl_down(sx,  off);
        sy  += __shfl_down(sy,  off);
    }
    __shared__ double red[3][4];
    const int wave = tid >> 6, lane = tid & 63;
    if (lane == 0) { red[0][wave] = sum; red[1][wave] = sx; red[2][wave] = sy; }
    __syncthreads();
    if (tid == 0) {
        const double S = red[0][0] + red[0][1] + red[0][2] + red[0][3];
        const double X = red[1][0] + red[1][1] + red[1][2] + red[1][3];
        const double Y = red[2][0] + red[2][1] + red[2][2] + red[2][3];
        ws[(size_t)(tensor * 3 + 0) * BK + bk] = S;
        ws[(size_t)(tensor * 3 + 1) * BK + bk] = X;
        ws[(size_t)(tensor * 3 + 2) * BK + bk] = Y;
        if (tensor == 0) out[OFF_ZETA + bk] = (float)S;
    }
}

// Kernel 2: keypoint extraction, one thread per (tensor, b, k).
__global__ __launch_bounds__(256)
void keypoint_kernel(const double* __restrict__ ws, float* __restrict__ out) {
    const int t = blockIdx.x * 256 + threadIdx.x;
    if (t >= 2 * BK) return;
    const int tensor = t / BK;
    const int bk     = t - tensor * BK;
    const int b = bk / K, k = bk - b * K;

    const double S = ws[(size_t)(tensor * 3 + 0) * BK + bk];
    const double X = ws[(size_t)(tensor * 3 + 1) * BK + bk];
    const double Y = ws[(size_t)(tensor * 3 + 2) * BK + bk];

    const float fz = (float)S;
    const float kx = rintf((float)X / fz);   // RNE matches jnp.round
    const float ky = rintf((float)Y / fz);

    const float* map     = out + (tensor ? OFF_TFDK : OFF_DK) + (size_t)bk * HW; // s, s1
    const float* mainmap = out + OFF_DK + (size_t)bk * HW;                       // s2 (bug-faithful)

    const int gx = (int)kx, gy = (int)ky;
    const float s = map[gy * W + gx];

    // mul then add (NOT fma) to match jnp's kp + kp*s, then int32 truncation
    const int kp1x = (int)__fadd_rn(kx, __fmul_rn(kx, s));
    const int kp1y = (int)__fadd_rn(ky, __fmul_rn(ky, s));
    const int kp2x = (int)__fsub_rn(kx, __fmul_rn(kx, s));
    const int kp2y = (int)__fsub_rn(ky, __fmul_rn(ky, s));

    const int w1 = min(max(kp1x, 0), W - 1), h1 = min(max(kp1y, 0), H - 1);
    const int w2 = min(max(kp2x, 0), W - 1), h2 = min(max(kp2y, 0), H - 1);
    const float s1 = map[h1 * W + w1];
    const float s2 = mainmap[h2 * W + w2];

    float* okp = out + (tensor ? OFF_TFKP : OFF_KP);
    float* r0 = okp + ((size_t)b * 3 * K + k) * 3;
    r0[0] = kx;           r0[1] = ky;           r0[2] = s;
    float* r1 = okp + ((size_t)b * 3 * K + K + k) * 3;
    r1[0] = (float)kp1x;  r1[1] = (float)kp1y;  r1[2] = s1;
    float* r2 = okp + ((size_t)b * 3 * K + 2 * K + k) * 3;
    r2[0] = (float)kp2x;  r2[1] = (float)kp2y;  r2[2] = s2;
}

extern "C" void kernel_launch(void* const* d_in, const int* in_sizes, int n_in,
                              void* d_out, int out_size, void* d_ws, size_t ws_size,
                              hipStream_t stream) {
    const float* Rk   = (const float*)d_in[0];
    const float* tfRk = (const float*)d_in[1];
    float*  out = (float*)d_out;
    double* ws  = (double*)d_ws;   // needs 2*3*1600*8 = 76.8 KB

    sigmoid_reduce_kernel<<<2 * BK, 256, 0, stream>>>(Rk, tfRk, out, ws);
    const int nkp = 2 * BK;
    keypoint_kernel<<<(nkp + 255) / 256, 256, 0, stream>>>(ws, out);
}

// Round 4
// 114.556 us; speedup vs baseline: 1.5552x; 1.5552x over previous
//
#include <hip/hip_runtime.h>
#include <hip/hip_bf16.h>

// Problem geometry (fixed by the reference)
constexpr int B = 16, K = 100, H = 120, W = 160;
constexpr int HW  = H * W;          // 19200
constexpr int NF4 = HW / 4;         // 4800 float4 per map
constexpr int BK  = B * K;          // 1600 maps per tensor
constexpr int W4  = W / 4;          // 40 float4 per row

// Flat f32 output layout (concatenated in reference return order)
constexpr size_t OFF_DK   = 0;                       // Dk        [B,K,H,W]
constexpr size_t OFF_KP   = (size_t)BK * HW;         // keypoint  [B,3K,3]
constexpr size_t OFF_ZETA = OFF_KP + (size_t)B*3*K*3;// get_zeta  [B,K]
constexpr size_t OFF_TFDK = OFF_ZETA + BK;           // tf_Dk     [B,K,H,W]
constexpr size_t OFF_TFKP = OFF_TFDK + (size_t)BK*HW;// tf_keypoint [B,3K,3]

typedef float f32x4 __attribute__((ext_vector_type(4)));

__device__ __forceinline__ float sigmoidf(float x) {
    return 1.0f / (1.0f + expf(-x));
}

// Kernel 1: sigmoid + per-map reductions.
// grid.x = 2*BK blocks; block handles one (tensor, b, k) map.
// 2x-paired float4 loads (32B/lane in flight), normal (cached) streams —
// nontemporal hints measured -60% (write amplification, round 3).
__global__ __launch_bounds__(256)
void sigmoid_reduce_kernel(const float* __restrict__ Rk,
                           const float* __restrict__ tfRk,
                           float* __restrict__ out,
                           double* __restrict__ ws) {
    const int blk    = blockIdx.x;
    const int tensor = (blk >= BK) ? 1 : 0;
    const int bk     = blk - tensor * BK;
    const float* src = tensor ? tfRk : Rk;
    float*       dst = out + (tensor ? OFF_TFDK : OFF_DK);

    const f32x4* __restrict__ s4 = (const f32x4*)(src + (size_t)bk * HW);
    f32x4*       __restrict__ d4 = (f32x4*)(dst + (size_t)bk * HW);

    const int tid = threadIdx.x;
    double sum = 0.0, sx = 0.0, sy = 0.0;

    // pairs: i0 = 512*n + 2*tid, i1 = i0+1.  NF4=4800 is even, so pairs never split.
    for (int i0 = 2 * tid; i0 < NF4; i0 += 512) {
        const int i1 = i0 + 1;
        f32x4 va = s4[i0];
        f32x4 vb = s4[i1];

        f32x4 oa, ob;
        oa.x = sigmoidf(va.x); oa.y = sigmoidf(va.y);
        oa.z = sigmoidf(va.z); oa.w = sigmoidf(va.w);
        ob.x = sigmoidf(vb.x); ob.y = sigmoidf(vb.y);
        ob.z = sigmoidf(vb.z); ob.w = sigmoidf(vb.w);

        d4[i0] = oa;
        d4[i1] = ob;

        {
            const int y  = i0 / W4;
            const int x0 = (i0 - y * W4) * 4;
            const double d0 = oa.x, d1 = oa.y, d2 = oa.z, d3 = oa.w;
            const double rs = d0 + d1 + d2 + d3;
            sum += rs;
            sy  += rs * (double)y;
            sx  += d0 * (double)(x0)     + d1 * (double)(x0 + 1)
                 + d2 * (double)(x0 + 2) + d3 * (double)(x0 + 3);
        }
        {
            const int y  = i1 / W4;
            const int x0 = (i1 - y * W4) * 4;
            const double d0 = ob.x, d1 = ob.y, d2 = ob.z, d3 = ob.w;
            const double rs = d0 + d1 + d2 + d3;
            sum += rs;
            sy  += rs * (double)y;
            sx  += d0 * (double)(x0)     + d1 * (double)(x0 + 1)
                 + d2 * (double)(x0 + 2) + d3 * (double)(x0 + 3);
        }
    }

    // wave (64-lane) reduction
    for (int off = 32; off > 0; off >>= 1) {
        sum += __shfl_down(sum, off);
        sx  += __shfl_down(sx,  off);
        sy  += __shfl_down(sy,  off);
    }
    __shared__ double red[3][4];
    const int wave = tid >> 6, lane = tid & 63;
    if (lane == 0) { red[0][wave] = sum; red[1][wave] = sx; red[2][wave] = sy; }
    __syncthreads();
    if (tid == 0) {
        const double S = red[0][0] + red[0][1] + red[0][2] + red[0][3];
        const double X = red[1][0] + red[1][1] + red[1][2] + red[1][3];
        const double Y = red[2][0] + red[2][1] + red[2][2] + red[2][3];
        ws[(size_t)(tensor * 3 + 0) * BK + bk] = S;
        ws[(size_t)(tensor * 3 + 1) * BK + bk] = X;
        ws[(size_t)(tensor * 3 + 2) * BK + bk] = Y;
        if (tensor == 0) out[OFF_ZETA + bk] = (float)S;
    }
}

// Kernel 2: keypoint extraction, one thread per (tensor, b, k).
__global__ __launch_bounds__(256)
void keypoint_kernel(const double* __restrict__ ws, float* __restrict__ out) {
    const int t = blockIdx.x * 256 + threadIdx.x;
    if (t >= 2 * BK) return;
    const int tensor = t / BK;
    const int bk     = t - tensor * BK;
    const int b = bk / K, k = bk - b * K;

    const double S = ws[(size_t)(tensor * 3 + 0) * BK + bk];
    const double X = ws[(size_t)(tensor * 3 + 1) * BK + bk];
    const double Y = ws[(size_t)(tensor * 3 + 2) * BK + bk];

    const float fz = (float)S;
    const float kx = rintf((float)X / fz);   // RNE matches jnp.round
    const float ky = rintf((float)Y / fz);

    const float* map     = out + (tensor ? OFF_TFDK : OFF_DK) + (size_t)bk * HW; // s, s1
    const float* mainmap = out + OFF_DK + (size_t)bk * HW;                       // s2 (bug-faithful)

    const int gx = (int)kx, gy = (int)ky;
    const float s = map[gy * W + gx];

    // mul then add (NOT fma) to match jnp's kp + kp*s, then int32 truncation
    const int kp1x = (int)__fadd_rn(kx, __fmul_rn(kx, s));
    const int kp1y = (int)__fadd_rn(ky, __fmul_rn(ky, s));
    const int kp2x = (int)__fsub_rn(kx, __fmul_rn(kx, s));
    const int kp2y = (int)__fsub_rn(ky, __fmul_rn(ky, s));

    const int w1 = min(max(kp1x, 0), W - 1), h1 = min(max(kp1y, 0), H - 1);
    const int w2 = min(max(kp2x, 0), W - 1), h2 = min(max(kp2y, 0), H - 1);
    const float s1 = map[h1 * W + w1];
    const float s2 = mainmap[h2 * W + w2];

    float* okp = out + (tensor ? OFF_TFKP : OFF_KP);
    float* r0 = okp + ((size_t)b * 3 * K + k) * 3;
    r0[0] = kx;           r0[1] = ky;           r0[2] = s;
    float* r1 = okp + ((size_t)b * 3 * K + K + k) * 3;
    r1[0] = (float)kp1x;  r1[1] = (float)kp1y;  r1[2] = s1;
    float* r2 = okp + ((size_t)b * 3 * K + 2 * K + k) * 3;
    r2[0] = (float)kp2x;  r2[1] = (float)kp2y;  r2[2] = s2;
}

extern "C" void kernel_launch(void* const* d_in, const int* in_sizes, int n_in,
                              void* d_out, int out_size, void* d_ws, size_t ws_size,
                              hipStream_t stream) {
    const float* Rk   = (const float*)d_in[0];
    const float* tfRk = (const float*)d_in[1];
    float*  out = (float*)d_out;
    double* ws  = (double*)d_ws;   // needs 2*3*1600*8 = 76.8 KB

    sigmoid_reduce_kernel<<<2 * BK, 256, 0, stream>>>(Rk, tfRk, out, ws);
    const int nkp = 2 * BK;
    keypoint_kernel<<<(nkp + 255) / 256, 256, 0, stream>>>(ws, out);
}

// Round 5
// 108.397 us; speedup vs baseline: 1.6435x; 1.0568x over previous
//
#include <hip/hip_runtime.h>
#include <hip/hip_bf16.h>

// Problem geometry (fixed by the reference)
constexpr int B = 16, K = 100, H = 120, W = 160;
constexpr int HW  = H * W;          // 19200
constexpr int NF4 = HW / 4;         // 4800 float4 per map
constexpr int BK  = B * K;          // 1600 maps per tensor
constexpr int W4  = W / 4;          // 40 float4 per row

// Flat f32 output layout (concatenated in reference return order)
constexpr size_t OFF_DK   = 0;                       // Dk        [B,K,H,W]
constexpr size_t OFF_KP   = (size_t)BK * HW;         // keypoint  [B,3K,3]
constexpr size_t OFF_ZETA = OFF_KP + (size_t)B*3*K*3;// get_zeta  [B,K]
constexpr size_t OFF_TFDK = OFF_ZETA + BK;           // tf_Dk     [B,K,H,W]
constexpr size_t OFF_TFKP = OFF_TFDK + (size_t)BK*HW;// tf_keypoint [B,3K,3]

typedef float f32x4 __attribute__((ext_vector_type(4)));

// native-rate sigmoid: rcp(1 + exp2(-x*log2e)); v_exp_f32 + v_rcp_f32 are
// ~1 ulp — far inside the 2%-of-max harness threshold.
__device__ __forceinline__ float fast_sigmoid(float x) {
    const float e = __builtin_amdgcn_exp2f(-1.44269504088896340736f * x);
    return __builtin_amdgcn_rcpf(1.0f + e);
}

// Kernel 1: sigmoid + per-map reductions (f32 accumulation).
// grid.x = 2*BK blocks; block handles one (tensor, b, k) map.
__global__ __launch_bounds__(256)
void sigmoid_reduce_kernel(const float* __restrict__ Rk,
                           const float* __restrict__ tfRk,
                           float* __restrict__ out,
                           float* __restrict__ ws) {
    const int blk    = blockIdx.x;
    const int tensor = (blk >= BK) ? 1 : 0;
    const int bk     = blk - tensor * BK;
    const float* src = tensor ? tfRk : Rk;
    float*       dst = out + (tensor ? OFF_TFDK : OFF_DK);

    const f32x4* __restrict__ s4 = (const f32x4*)(src + (size_t)bk * HW);
    f32x4*       __restrict__ d4 = (f32x4*)(dst + (size_t)bk * HW);

    const int tid = threadIdx.x;
    float sum = 0.0f, sx = 0.0f, sy = 0.0f;

    for (int i = tid; i < NF4; i += 256) {
        f32x4 v = s4[i];
        f32x4 o;
        o.x = fast_sigmoid(v.x);
        o.y = fast_sigmoid(v.y);
        o.z = fast_sigmoid(v.z);
        o.w = fast_sigmoid(v.w);
        d4[i] = o;

        const int y  = i / W4;                 // magic-mul, amortized over 4 elems
        const int x0 = (i - y * W4) * 4;
        const float rs = (o.x + o.y) + (o.z + o.w);
        sum += rs;
        sy  = fmaf(rs, (float)y, sy);
        sx  = fmaf(o.x, (float)(x0),     sx);
        sx  = fmaf(o.y, (float)(x0 + 1), sx);
        sx  = fmaf(o.z, (float)(x0 + 2), sx);
        sx  = fmaf(o.w, (float)(x0 + 3), sx);
    }

    // wave (64-lane) reduction
    for (int off = 32; off > 0; off >>= 1) {
        sum += __shfl_down(sum, off);
        sx  += __shfl_down(sx,  off);
        sy  += __shfl_down(sy,  off);
    }
    __shared__ float red[3][4];
    const int wave = tid >> 6, lane = tid & 63;
    if (lane == 0) { red[0][wave] = sum; red[1][wave] = sx; red[2][wave] = sy; }
    __syncthreads();
    if (tid == 0) {
        const float S = (red[0][0] + red[0][1]) + (red[0][2] + red[0][3]);
        const float X = (red[1][0] + red[1][1]) + (red[1][2] + red[1][3]);
        const float Y = (red[2][0] + red[2][1]) + (red[2][2] + red[2][3]);
        ws[(size_t)(tensor * 3 + 0) * BK + bk] = S;
        ws[(size_t)(tensor * 3 + 1) * BK + bk] = X;
        ws[(size_t)(tensor * 3 + 2) * BK + bk] = Y;
        if (tensor == 0) out[OFF_ZETA + bk] = S;
    }
}

// Kernel 2: keypoint extraction, one thread per (tensor, b, k).
__global__ __launch_bounds__(256)
void keypoint_kernel(const float* __restrict__ ws, float* __restrict__ out) {
    const int t = blockIdx.x * 256 + threadIdx.x;
    if (t >= 2 * BK) return;
    const int tensor = t / BK;
    const int bk     = t - tensor * BK;
    const int b = bk / K, k = bk - b * K;

    const float S = ws[(size_t)(tensor * 3 + 0) * BK + bk];
    const float X = ws[(size_t)(tensor * 3 + 1) * BK + bk];
    const float Y = ws[(size_t)(tensor * 3 + 2) * BK + bk];

    const float kx = rintf(X / S);   // RNE matches jnp.round
    const float ky = rintf(Y / S);

    const float* map     = out + (tensor ? OFF_TFDK : OFF_DK) + (size_t)bk * HW; // s, s1
    const float* mainmap = out + OFF_DK + (size_t)bk * HW;                       // s2 (bug-faithful)

    const int gx = (int)kx, gy = (int)ky;
    const float s = map[gy * W + gx];

    // mul then add (NOT fma) to match jnp's kp + kp*s, then int32 truncation
    const int kp1x = (int)__fadd_rn(kx, __fmul_rn(kx, s));
    const int kp1y = (int)__fadd_rn(ky, __fmul_rn(ky, s));
    const int kp2x = (int)__fsub_rn(kx, __fmul_rn(kx, s));
    const int kp2y = (int)__fsub_rn(ky, __fmul_rn(ky, s));

    const int w1 = min(max(kp1x, 0), W - 1), h1 = min(max(kp1y, 0), H - 1);
    const int w2 = min(max(kp2x, 0), W - 1), h2 = min(max(kp2y, 0), H - 1);
    const float s1 = map[h1 * W + w1];
    const float s2 = mainmap[h2 * W + w2];

    float* okp = out + (tensor ? OFF_TFKP : OFF_KP);
    float* r0 = okp + ((size_t)b * 3 * K + k) * 3;
    r0[0] = kx;           r0[1] = ky;           r0[2] = s;
    float* r1 = okp + ((size_t)b * 3 * K + K + k) * 3;
    r1[0] = (float)kp1x;  r1[1] = (float)kp1y;  r1[2] = s1;
    float* r2 = okp + ((size_t)b * 3 * K + 2 * K + k) * 3;
    r2[0] = (float)kp2x;  r2[1] = (float)kp2y;  r2[2] = s2;
}

extern "C" void kernel_launch(void* const* d_in, const int* in_sizes, int n_in,
                              void* d_out, int out_size, void* d_ws, size_t ws_size,
                              hipStream_t stream) {
    const float* Rk   = (const float*)d_in[0];
    const float* tfRk = (const float*)d_in[1];
    float* out = (float*)d_out;
    float* ws  = (float*)d_ws;   // needs 2*3*1600*4 = 38.4 KB

    sigmoid_reduce_kernel<<<2 * BK, 256, 0, stream>>>(Rk, tfRk, out, ws);
    const int nkp = 2 * BK;
    keypoint_kernel<<<(nkp + 255) / 256, 256, 0, stream>>>(ws, out);
}

// Round 6
// 105.686 us; speedup vs baseline: 1.6857x; 1.0257x over previous
//
#include <hip/hip_runtime.h>
#include <hip/hip_bf16.h>

// Problem geometry (fixed by the reference)
constexpr int B = 16, K = 100, H = 120, W = 160;
constexpr int HW  = H * W;          // 19200
constexpr int NF4 = HW / 4;         // 4800 float4 per map
constexpr int BK  = B * K;          // 1600 maps per tensor
constexpr int W4  = W / 4;          // 40 float4 per row

// Flat f32 output layout (concatenated in reference return order)
constexpr size_t OFF_DK   = 0;                       // Dk        [B,K,H,W]
constexpr size_t OFF_KP   = (size_t)BK * HW;         // keypoint  [B,3K,3]
constexpr size_t OFF_ZETA = OFF_KP + (size_t)B*3*K*3;// get_zeta  [B,K]
constexpr size_t OFF_TFDK = OFF_ZETA + BK;           // tf_Dk     [B,K,H,W]
constexpr size_t OFF_TFKP = OFF_TFDK + (size_t)BK*HW;// tf_keypoint [B,3K,3]

typedef float f32x4 __attribute__((ext_vector_type(4)));
typedef float f32x2 __attribute__((ext_vector_type(2)));

// native-rate sigmoid: rcp(1 + exp2(-x*log2e)); identical sequence everywhere
// so recomputed gathers are bit-identical to the stored map values.
__device__ __forceinline__ float fast_sigmoid(float x) {
    const float e = __builtin_amdgcn_exp2f(-1.44269504088896340736f * x);
    return __builtin_amdgcn_rcpf(1.0f + e);
}

// Single fused kernel: sigmoid stream + per-map reduction + keypoint row.
// grid.x = 2*BK blocks; block handles one (tensor, b, k) map.
// Keypoint gathers recompute sigmoid from the READ-ONLY INPUTS (coherent
// across XCDs), so no second kernel / cross-block dependency is needed.
__global__ __launch_bounds__(256)
void fused_kernel(const float* __restrict__ Rk,
                  const float* __restrict__ tfRk,
                  float* __restrict__ out) {
    const int blk    = blockIdx.x;
    const int tensor = (blk >= BK) ? 1 : 0;
    const int bk     = blk - tensor * BK;
    const float* src = tensor ? tfRk : Rk;
    float*       dst = out + (tensor ? OFF_TFDK : OFF_DK);

    const f32x4* __restrict__ s4 = (const f32x4*)(src + (size_t)bk * HW);
    f32x4*       __restrict__ d4 = (f32x4*)(dst + (size_t)bk * HW);

    const int tid = threadIdx.x;
    f32x2 sum2 = {0.0f, 0.0f}, sx2 = {0.0f, 0.0f}, sy2 = {0.0f, 0.0f};

    for (int i = tid; i < NF4; i += 256) {
        f32x4 v = s4[i];
        f32x4 o;
        o.x = fast_sigmoid(v.x);
        o.y = fast_sigmoid(v.y);
        o.z = fast_sigmoid(v.z);
        o.w = fast_sigmoid(v.w);
        d4[i] = o;

        const int y  = i / W4;
        const int x0 = (i - y * W4) * 4;
        const float fy = (float)y, fx0 = (float)x0;

        const f32x2 lo = {o.x, o.y}, hi = {o.z, o.w};
        const f32x2 rs = lo + hi;                       // {x+z, y+w}
        sum2 += rs;
        const f32x2 yy = {fy, fy};
        sy2 = rs * yy + sy2;                            // v_pk_fma_f32
        const f32x2 xlo = {fx0,        fx0 + 1.0f};
        const f32x2 xhi = {fx0 + 2.0f, fx0 + 3.0f};
        sx2 = lo * xlo + sx2;
        sx2 = hi * xhi + sx2;
    }

    float sum = sum2.x + sum2.y;
    float sx  = sx2.x + sx2.y;
    float sy  = sy2.x + sy2.y;

    // wave (64-lane) reduction
    for (int off = 32; off > 0; off >>= 1) {
        sum += __shfl_down(sum, off);
        sx  += __shfl_down(sx,  off);
        sy  += __shfl_down(sy,  off);
    }
    __shared__ float red[3][4];
    const int wave = tid >> 6, lane = tid & 63;
    if (lane == 0) { red[0][wave] = sum; red[1][wave] = sx; red[2][wave] = sy; }
    __syncthreads();

    if (tid == 0) {
        const float S = (red[0][0] + red[0][1]) + (red[0][2] + red[0][3]);
        const float X = (red[1][0] + red[1][1]) + (red[1][2] + red[1][3]);
        const float Y = (red[2][0] + red[2][1]) + (red[2][2] + red[2][3]);

        const int b = bk / K, k = bk - b * K;
        if (tensor == 0) out[OFF_ZETA + bk] = S;

        const float kx = rintf(X / S);   // RNE matches jnp.round
        const float ky = rintf(Y / S);

        // gathers from the INPUTS, sigmoid recomputed (bit-identical)
        const float* imap  = src + (size_t)bk * HW;   // own map (s, s1)
        const float* imain = Rk  + (size_t)bk * HW;   // main map (s2, bug-faithful)

        const int gx = (int)kx, gy = (int)ky;
        const float s = fast_sigmoid(imap[gy * W + gx]);

        // mul then add (NOT fma) to match jnp's kp + kp*s, then int32 truncation
        const int kp1x = (int)__fadd_rn(kx, __fmul_rn(kx, s));
        const int kp1y = (int)__fadd_rn(ky, __fmul_rn(ky, s));
        const int kp2x = (int)__fsub_rn(kx, __fmul_rn(kx, s));
        const int kp2y = (int)__fsub_rn(ky, __fmul_rn(ky, s));

        const int w1 = min(max(kp1x, 0), W - 1), h1 = min(max(kp1y, 0), H - 1);
        const int w2 = min(max(kp2x, 0), W - 1), h2 = min(max(kp2y, 0), H - 1);
        const float s1 = fast_sigmoid(imap [h1 * W + w1]);
        const float s2 = fast_sigmoid(imain[h2 * W + w2]);

        float* okp = out + (tensor ? OFF_TFKP : OFF_KP);
        float* r0 = okp + ((size_t)b * 3 * K + k) * 3;
        r0[0] = kx;           r0[1] = ky;           r0[2] = s;
        float* r1 = okp + ((size_t)b * 3 * K + K + k) * 3;
        r1[0] = (float)kp1x;  r1[1] = (float)kp1y;  r1[2] = s1;
        float* r2 = okp + ((size_t)b * 3 * K + 2 * K + k) * 3;
        r2[0] = (float)kp2x;  r2[1] = (float)kp2y;  r2[2] = s2;
    }
}

extern "C" void kernel_launch(void* const* d_in, const int* in_sizes, int n_in,
                              void* d_out, int out_size, void* d_ws, size_t ws_size,
                              hipStream_t stream) {
    const float* Rk   = (const float*)d_in[0];
    const float* tfRk = (const float*)d_in[1];
    float* out = (float*)d_out;

    fused_kernel<<<2 * BK, 256, 0, stream>>>(Rk, tfRk, out);
}